// Round 11
// baseline (502.442 us; speedup 1.0000x reference)
//
#include <hip/hip_runtime.h>

typedef unsigned short u16;
typedef __bf16 bf16_t;
typedef bf16_t bf16x8 __attribute__((ext_vector_type(8)));
typedef float f32x4 __attribute__((ext_vector_type(4)));
typedef float f32x16 __attribute__((ext_vector_type(16)));

#define LOG2E 1.4426950408889634f
#define QKVS 6144  // row stride of fused QKV activation buffer

__device__ __forceinline__ u16 f2bf(float f) {
  union { float f; unsigned u; } c; c.f = f;
  unsigned r = c.u + 0x7fffu + ((c.u >> 16) & 1u);
  return (u16)(r >> 16);
}
__device__ __forceinline__ float bf2f(u16 u) {
  union { unsigned u; float f; } c; c.u = ((unsigned)u) << 16;
  return c.f;
}

__device__ __forceinline__ void gload16(const void* g, void* l) {
  __builtin_amdgcn_global_load_lds(
      (const __attribute__((address_space(1))) unsigned int*)g,
      (__attribute__((address_space(3))) unsigned int*)l, 16, 0, 0);
}

__device__ __forceinline__ unsigned cvtpk(float lo, float hi) {
  unsigned r;
  asm("v_cvt_pk_bf16_f32 %0, %1, %2" : "=v"(r) : "v"(lo), "v"(hi));
  return r;
}
__device__ __forceinline__ void swap32(unsigned& a, unsigned& b) {
  asm("v_permlane32_swap_b32 %0, %1" : "+v"(a), "+v"(b));
}

#define MFMA16(a, b, c) __builtin_amdgcn_mfma_f32_16x16x32_bf16((a), (b), (c), 0, 0, 0)
#define MFMA32(a, b, c) __builtin_amdgcn_mfma_f32_32x32x16_bf16((a), (b), (c), 0, 0, 0)

// ---------------- prep kernels ----------------

__global__ __launch_bounds__(256) void k_convert_f32_bf16(const float* __restrict__ in,
                                                          u16* __restrict__ out, int n4) {
  int i = blockIdx.x * 256 + threadIdx.x;
  if (i >= n4) return;
  float4 v = ((const float4*)in)[i];
  ushort4 o;
  o.x = f2bf(v.x); o.y = f2bf(v.y); o.z = f2bf(v.z); o.w = f2bf(v.w);
  ((ushort4*)out)[i] = o;
}

// out[C][R] = bf16(in[R][C])
__global__ __launch_bounds__(256) void k_transpose_f32_bf16(const float* __restrict__ in,
                                                            u16* __restrict__ out, int R, int C) {
  __shared__ float tile[32][33];
  int tx = threadIdx.x, ty = threadIdx.y;
  int bx = blockIdx.x * 32, by = blockIdx.y * 32;
#pragma unroll
  for (int i = 0; i < 4; i++)
    tile[ty + i * 8][tx] = in[(size_t)(by + ty + i * 8) * C + bx + tx];
  __syncthreads();
#pragma unroll
  for (int i = 0; i < 4; i++)
    out[(size_t)(bx + ty + i * 8) * R + by + tx] = f2bf(tile[tx][ty + i * 8]);
}

// out[col][row] = in[row][col]; in row-stride C, out row-stride R
__global__ __launch_bounds__(256) void k_transpose_bf16(const u16* __restrict__ in,
                                                        u16* __restrict__ out, int R, int C) {
  __shared__ u16 tile[32][33];
  int tx = threadIdx.x, ty = threadIdx.y;
  int bx = blockIdx.x * 32, by = blockIdx.y * 32;
#pragma unroll
  for (int i = 0; i < 4; i++)
    tile[ty + i * 8][tx] = in[(size_t)(by + ty + i * 8) * C + bx + tx];
  __syncthreads();
#pragma unroll
  for (int i = 0; i < 4; i++)
    out[(size_t)(bx + ty + i * 8) * R + by + tx] = tile[tx][ty + i * 8];
}

// ---------------- RoPE (in place, bf16) ----------------
__global__ __launch_bounds__(256) void k_rope(u16* __restrict__ x, const int* __restrict__ pos,
                                              int nh_mask, int nh_shift, int width) {
  int idx = blockIdx.x * 256 + threadIdx.x;
  int i = idx & 127;
  int h = (idx >> 7) & nh_mask;
  int row = idx >> (7 + nh_shift);
  int p = pos[row];
  float f = (float)p * exp2f((float)i * (-13.287712379549449f / 128.f));
  float sn, cs;
  sincosf(f, &sn, &cs);
  size_t base = (size_t)row * width + h * 256 + i;
  float x1 = bf2f(x[base]), x2 = bf2f(x[base + 128]);
  x[base] = f2bf(x1 * cs - x2 * sn);
  x[base + 128] = f2bf(x2 * cs + x1 * sn);
}

// ---------------- GEMM m97-style (kept for out-proj) ----------------

template <int OUT_BF16>
__global__ __launch_bounds__(256) void k_gemm_bt(const u16* __restrict__ A,
                                                 const u16* __restrict__ Bt,
                                                 void* __restrict__ C, int M, int N, int K) {
  __shared__ u16 As[128 * 64];
  __shared__ u16 Bs[128 * 64];
  const int tid = threadIdx.x;
  const int lane = tid & 63;
  const int w = tid >> 6;
  const int l15 = lane & 15, l4 = lane >> 4;
  const int wr = w >> 1, wc = w & 1;
  const int bx = blockIdx.x, by = blockIdx.y;

  f32x4 acc[4][4];
#pragma unroll
  for (int a = 0; a < 4; a++)
#pragma unroll
    for (int b2 = 0; b2 < 4; b2++) acc[a][b2] = (f32x4){0.f, 0.f, 0.f, 0.f};

  const u16* Abase = A + (size_t)by * 128 * K;
  const u16* Bbase = Bt + (size_t)bx * 128 * K;

  for (int kk = 0; kk < K; kk += 64) {
    __syncthreads();
#pragma unroll
    for (int j = 0; j < 4; j++) {
      int ci = w * 256 + j * 64 + lane;
      int row = ci >> 3, c = ci & 7;
      gload16(Abase + (size_t)row * K + kk + c * 8, (char*)As + ci * 16);
      gload16(Bbase + (size_t)row * K + kk + c * 8, (char*)Bs + ci * 16);
    }
    __syncthreads();
#pragma unroll
    for (int kc = 0; kc < 2; kc++) {
      int kb = kc * 64 + l4 * 16;
      bf16x8 av[4], bv[4];
#pragma unroll
      for (int mt = 0; mt < 4; mt++)
        av[mt] = *(const bf16x8*)((const char*)As + (wr * 64 + mt * 16 + l15) * 128 + kb);
#pragma unroll
      for (int nt = 0; nt < 4; nt++)
        bv[nt] = *(const bf16x8*)((const char*)Bs + (wc * 64 + nt * 16 + l15) * 128 + kb);
#pragma unroll
      for (int mt = 0; mt < 4; mt++)
#pragma unroll
        for (int nt = 0; nt < 4; nt++) acc[mt][nt] = MFMA16(av[mt], bv[nt], acc[mt][nt]);
    }
  }
#pragma unroll
  for (int mt = 0; mt < 4; mt++) {
#pragma unroll
    for (int nt = 0; nt < 4; nt++) {
      int col = bx * 128 + wc * 64 + nt * 16 + l15;
#pragma unroll
      for (int r = 0; r < 4; r++) {
        int row = by * 128 + wr * 64 + mt * 16 + l4 * 4 + r;
        if (OUT_BF16)
          ((u16*)C)[(size_t)row * N + col] = f2bf(acc[mt][nt][r]);
        else
          ((float*)C)[(size_t)row * N + col] = acc[mt][nt][r];
      }
    }
  }
}

// ---------------- GEMM 256x256 8-phase (r10, race-safe) ----------------

__global__ __launch_bounds__(512, 1) void k_gemm256(const u16* __restrict__ A,
                                                    const u16* __restrict__ Bt,
                                                    u16* __restrict__ C, int N, int K) {
  extern __shared__ char smem[];
  const int tid = threadIdx.x;
  const int lane = tid & 63, w = tid >> 6;
  const int l15 = lane & 15, l4 = lane >> 4;
  const int wr = w >> 2, wc = w & 3;
  const int bx = blockIdx.x, by = blockIdx.y;
  const int NT = K >> 6;

  const u16* Ab = A + (size_t)(by * 256) * K;
  const u16* Bb = Bt + (size_t)(bx * 256) * K;

  int srcoff[2], dstoff[2];
#pragma unroll
  for (int rr = 0; rr < 2; rr++) {
    int ci = rr * 512 + tid;
    int lc = ci ^ (((ci >> 5) & 1) << 1);
    int kc = lc >> 9, row = (lc >> 2) & 127, g2 = lc & 3;
    srcoff[rr] = row * K + kc * 32 + g2 * 8;
    dstoff[rr] = ci * 16;
  }

  auto SH = [&](int Tg, int halfidx) {
    const u16* base = (halfidx < 2) ? (Ab + (size_t)(halfidx * 128) * K)
                                    : (Bb + (size_t)((halfidx - 2) * 128) * K);
    char* dst = smem + (Tg & 1) * 65536 + halfidx * 16384;
    int kk = Tg * 64;
#pragma unroll
    for (int rr = 0; rr < 2; rr++)
      gload16(base + srcoff[rr] + kk, dst + dstoff[rr]);
  };

  auto lda = [&](int c, int kc, int mrow4) -> bf16x8 {
    int L = kc * 8192 + (mrow4 * 16 + l15) * 64 + l4 * 16;
    int P = L ^ (((L >> 9) & 1) << 5);
    return *(const bf16x8*)(smem + c * 65536 + wr * 16384 + P);
  };
  auto ldb = [&](int c, int kc, int j) -> bf16x8 {
    int L = kc * 8192 + ((wc & 1) * 64 + j * 16 + l15) * 64 + l4 * 16;
    int P = L ^ (((L >> 9) & 1) << 5);
    return *(const bf16x8*)(smem + c * 65536 + 32768 + (wc >> 1) * 16384 + P);
  };

  f32x4 acc[8][4];
#pragma unroll
  for (int i = 0; i < 8; i++)
#pragma unroll
    for (int j = 0; j < 4; j++) acc[i][j] = (f32x4){0.f, 0.f, 0.f, 0.f};

  SH(0, 0); SH(0, 1); SH(0, 2); SH(0, 3);
  SH(1, 2); SH(1, 3);
  asm volatile("s_waitcnt vmcnt(4)" ::: "memory");
  __builtin_amdgcn_s_barrier();
  asm volatile("" ::: "memory");

  bf16x8 bv[2][4];
  for (int T = 0; T < NT; ++T) {
    const int c = T & 1;
#pragma unroll
    for (int q = 0; q < 4; q++) {
      const int kc = q & 1, mh = q >> 1;
      bf16x8 av[4];
      if (q < 2) {
#pragma unroll
        for (int j = 0; j < 4; j++) bv[kc][j] = ldb(c, kc, j);
      }
#pragma unroll
      for (int ii = 0; ii < 4; ii++) av[ii] = lda(c, kc, mh * 4 + ii);
      if (q == 0)      { if (T + 1 < NT) SH(T + 1, 0); }
      else if (q == 1) { if (T + 1 < NT) SH(T + 1, 1); }
      else if (q == 2) { if (T + 2 < NT) SH(T + 2, 2); }
      else             { if (T + 2 < NT) SH(T + 2, 3); }
      if (q == 3) {
        if (T < NT - 2)       asm volatile("s_waitcnt vmcnt(4)" ::: "memory");
        else if (T == NT - 2) asm volatile("s_waitcnt vmcnt(0)" ::: "memory");
      }
      asm volatile("" ::: "memory");
      __builtin_amdgcn_s_barrier();
      asm volatile("" ::: "memory");
      asm volatile("s_waitcnt lgkmcnt(0)" ::: "memory");
      __builtin_amdgcn_sched_barrier(0);
      __builtin_amdgcn_s_setprio(1);
#pragma unroll
      for (int ii = 0; ii < 4; ii++)
#pragma unroll
        for (int j = 0; j < 4; j++)
          acc[mh * 4 + ii][j] = MFMA16(av[ii], bv[kc][j], acc[mh * 4 + ii][j]);
      __builtin_amdgcn_s_setprio(0);
      asm volatile("" ::: "memory");
      __builtin_amdgcn_s_barrier();
      asm volatile("" ::: "memory");
    }
  }

#pragma unroll
  for (int i = 0; i < 8; i++) {
#pragma unroll
    for (int j = 0; j < 4; j++) {
      int col = bx * 256 + wc * 64 + j * 16 + l15;
#pragma unroll
      for (int r = 0; r < 4; r++) {
        int row = by * 256 + wr * 128 + i * 16 + l4 * 4 + r;
        C[(size_t)row * N + col] = f2bf(acc[i][j][r]);
      }
    }
  }
}

// ---------------- flash attention: intra-block split-KV ----------------
// 512 threads = 2 groups x 4 waves. Heavy blocks (qb 8..15): group g does KV
// tiles [g*half, (g+1)*half), half = 2qb+2 (even); LDS online-softmax merge at
// end. Light blocks (qb 0..7): groups handle different heads (same qb/b/kv ->
// equal trips; group0 stages, both read). XCD affinity: flat%8 -> (b,kv).
// LDS: 128 KB staging (2 groups x {K0,K1,V0,V1} x 16 KB) + 1 KB m/l exchange.
// Merge reuses the dead staging LDS for the o exchange (f32, 128 KB exact).

__global__ __launch_bounds__(512, 1) void k_attn(const u16* __restrict__ QKV,
                                                 const u16* __restrict__ Vt,
                                                 u16* __restrict__ AO) {
  __shared__ __align__(16) char sbuf[131072];
  __shared__ float mlx[256];

  const int tid = threadIdx.x, lane = tid & 63;
  const int wg = tid >> 6, g = wg >> 2, w = wg & 3;
  const int r31 = lane & 31, hi = lane >> 5;

  const int flat = blockIdx.x;
  const bool heavy = flat < 256;
  int b, kv, qb, h;
  if (heavy) {
    int r = flat & 7; b = r >> 2; kv = r & 3;
    int e = flat >> 3;
    qb = 15 - (e & 7);          // longest first
    h = kv * 4 + (e >> 3);
  } else {
    int f2 = flat - 256;
    int r = f2 & 7; b = r >> 2; kv = r & 3;
    int e = f2 >> 3;
    qb = 7 - (e & 7);
    h = kv * 4 + (e >> 3) * 2 + g;  // groups take adjacent heads
  }
  const int half = heavy ? (2 * qb + 2) : (4 * qb + 4);  // trips per group (even)
  const int t0 = heavy ? g * half : 0;
  const bool dostage = heavy || (g == 0);

  char* gb = sbuf + (heavy ? g : 0) * 65536;
  u16* K0 = (u16*)(gb);
  u16* K1 = (u16*)(gb + 16384);
  u16* V0 = (u16*)(gb + 32768);
  u16* V1 = (u16*)(gb + 49152);

  // Q fragments (B-operand): lane holds q-row r31, k-elems kc*16 + hi*8
  bf16x8 qreg[16];
  {
    const u16* qp = QKV + (size_t)(b * 2048 + qb * 128 + w * 32 + r31) * QKVS + h * 256 + hi * 8;
#pragma unroll
    for (int kc = 0; kc < 16; kc++) qreg[kc] = *(const bf16x8*)(qp + kc * 16);
  }

  f32x16 o[8];
#pragma unroll
  for (int df = 0; df < 8; df++)
#pragma unroll
    for (int jj = 0; jj < 16; jj++) o[df][jj] = 0.f;
  float mrow = -3e38f, lrow = 0.f;

  const int tlim = 4 * qb + w;
  const int qloc = qb * 128 + w * 32 + r31;
  const u16* Kbase = QKV + (size_t)(b * 2048) * QKVS + 4096 + kv * 256;
  const u16* Vbase = Vt + (size_t)(kv * 256) * 4096 + b * 2048;

  int kfix[4], vfix[4];
#pragma unroll
  for (int jj = 0; jj < 4; jj++) {
    int ci = jj * 256 + (tid & 255);  // per-group 256-thread staging pattern
    int krow = ci >> 5, kc = ci & 31;
    int kcg = (kc & 24) | ((kc ^ krow) & 7);
    kfix[jj] = krow * QKVS + kcg * 8;
    int vrow = ci >> 2, vc = ci & 3;
    int vg = (vc - (vrow >> 1)) & 3;
    vfix[jj] = vrow * 4096 + vg * 8;
  }
  int koff = t0 * 32 * QKVS, voff = t0 * 32;

  auto STAGE = [&](u16* Kd, u16* Vd) {
#pragma unroll
    for (int jj = 0; jj < 4; jj++)
      gload16(Kbase + kfix[jj] + koff, (char*)Kd + (jj * 256 + (tid & 255)) * 16);
#pragma unroll
    for (int jj = 0; jj < 4; jj++)
      gload16(Vbase + vfix[jj] + voff, (char*)Vd + (jj * 256 + (tid & 255)) * 16);
    koff += 32 * QKVS;
    voff += 32;
  };

  auto COMPUTE = [&](int t, const u16* Kc, const u16* Vc) {
    f32x16 s;
#pragma unroll
    for (int jj = 0; jj < 16; jj++) s[jj] = 0.f;
#pragma unroll
    for (int kc = 0; kc < 16; kc++) {
      int ch = kc * 2 + hi;
      int cs = (ch & 24) | ((ch ^ r31) & 7);
      bf16x8 kf = *(const bf16x8*)((const char*)Kc + r31 * 512 + cs * 16);
      s = MFMA32(kf, qreg[kc], s);
    }

    const float C = 0.0625f * LOG2E;
    float z[16];
#pragma unroll
    for (int jj = 0; jj < 16; jj++) z[jj] = s[jj] * C;
    if (t == tlim) {
#pragma unroll
      for (int jj = 0; jj < 16; jj++) {
        int kvg = t * 32 + (jj & 3) + 8 * (jj >> 2) + 4 * hi;
        if (kvg > qloc) z[jj] = -1e30f;
      }
    }

    float m0 = z[0];
#pragma unroll
    for (int jj = 1; jj < 16; jj++) m0 = fmaxf(m0, z[jj]);
    m0 = fmaxf(m0, __shfl_xor(m0, 32));
    if (__any(m0 > mrow + 11.54f)) {
      float mn = fmaxf(mrow, m0);
      float alpha = exp2f(mrow - mn);
      mrow = mn;
      lrow *= alpha;
#pragma unroll
      for (int jj = 0; jj < 16; jj++) {
        float a = __shfl(alpha, (jj & 3) + 8 * (jj >> 2) + 4 * hi);
#pragma unroll
        for (int df = 0; df < 8; df++) o[df][jj] *= a;
      }
    }
    float sum = 0.f;
#pragma unroll
    for (int jj = 0; jj < 16; jj++) {
      z[jj] = exp2f(z[jj] - mrow);
      sum += z[jj];
    }
    sum += __shfl_xor(sum, 32);
    lrow += sum;

    unsigned a0 = cvtpk(z[0], z[1]), a2 = cvtpk(z[4], z[5]);
    swap32(a0, a2);
    unsigned a1 = cvtpk(z[2], z[3]), a3 = cvtpk(z[6], z[7]);
    swap32(a1, a3);
    unsigned b0 = cvtpk(z[8], z[9]), b2 = cvtpk(z[12], z[13]);
    swap32(b0, b2);
    unsigned b1 = cvtpk(z[10], z[11]), b3 = cvtpk(z[14], z[15]);
    swap32(b1, b3);
    union UU { unsigned u[4]; bf16x8 v; };
    UU ua; ua.u[0] = a0; ua.u[1] = a1; ua.u[2] = a2; ua.u[3] = a3;
    UU ub; ub.u[0] = b0; ub.u[1] = b1; ub.u[2] = b2; ub.u[3] = b3;
    bf16x8 pa0 = ua.v, pa1 = ub.v;

#pragma unroll
    for (int df = 0; df < 8; df++) {
      int vr = df * 32 + r31;
      int c0 = (hi + (vr >> 1)) & 3;
      int c1 = (2 + hi + (vr >> 1)) & 3;
      bf16x8 v0 = *(const bf16x8*)((const char*)Vc + vr * 64 + c0 * 16);
      bf16x8 v1 = *(const bf16x8*)((const char*)Vc + vr * 64 + c1 * 16);
      o[df] = MFMA32(pa0, v0, o[df]);
      o[df] = MFMA32(pa1, v1, o[df]);
    }
  };

  if (dostage) STAGE(K0, V0);
  __syncthreads();

  for (int tt = 0; tt < half; tt += 2) {
    int t = t0 + tt;
    if (dostage) STAGE(K1, V1);  // tile t+1 (tt+1 < half always: half even)
    if (t <= tlim) COMPUTE(t, K0, V0);
    __syncthreads();
    if (dostage && tt + 2 < half) STAGE(K0, V0);
    if (t + 1 <= tlim) COMPUTE(t + 1, K1, V1);
    __syncthreads();
  }

  if (!heavy) {
    // direct normalized write (both groups, own head)
    float rl = 1.f / lrow;
    size_t rowbase = (size_t)(b * 2048 + qb * 128 + w * 32);
#pragma unroll
    for (int jj = 0; jj < 16; jj++) {
      float rr2 = __shfl(rl, (jj & 3) + 8 * (jj >> 2) + 4 * hi);
      int qr = (jj & 3) + 8 * (jj >> 2) + 4 * hi;
#pragma unroll
      for (int df = 0; df < 8; df++)
        AO[(rowbase + qr) * 4096 + h * 256 + df * 32 + r31] = f2bf(o[df][jj] * rr2);
    }
  } else {
    // merge the two KV-half partials via LDS (staging buffers are dead)
    float* X = (float*)sbuf;
    if (g == 1) {
      float* xw = X + w * 8192;
#pragma unroll
      for (int df = 0; df < 8; df++)
#pragma unroll
        for (int jj = 0; jj < 16; jj++) xw[(df * 16 + jj) * 64 + lane] = o[df][jj];
      if (lane < 32) {
        mlx[w * 32 + r31] = mrow;
        mlx[128 + w * 32 + r31] = lrow;
      }
    }
    __syncthreads();
    if (g == 0) {
      float m1 = mlx[w * 32 + r31], l1 = mlx[128 + w * 32 + r31];
      float mm = fmaxf(mrow, m1);
      float a0 = exp2f(mrow - mm), a1 = exp2f(m1 - mm);
      float rl = 1.f / (lrow * a0 + l1 * a1);
      const float* xw = X + w * 8192;
      size_t rowbase = (size_t)(b * 2048 + qb * 128 + w * 32);
#pragma unroll
      for (int jj = 0; jj < 16; jj++) {
        int qr = (jj & 3) + 8 * (jj >> 2) + 4 * hi;
        float A0 = __shfl(a0, qr), A1 = __shfl(a1, qr), RL = __shfl(rl, qr);
#pragma unroll
        for (int df = 0; df < 8; df++) {
          float v = o[df][jj] * A0 + xw[(df * 16 + jj) * 64 + lane] * A1;
          AO[(rowbase + qr) * 4096 + h * 256 + df * 32 + r31] = f2bf(v * RL);
        }
      }
    }
  }
}

// ---------------- host ----------------

// ws layout (bytes), high-water 109.1 MB:
// Xb @0 (16MB, dead after QKV gemm) -- AO @0 (32MB) aliases it + Wqkvt head.
// Wqkvt @16.7M (24MB), dead after gemm. Vt @33.5M (8MB) aliases Wqkvt tail.
// Wot @41.9M (16MB, persists). QKV @58.7M (48MB, [4096][6144]).
#define OFF_AO    0u
#define OFF_XB    0u
#define OFF_WQKVT 16777216u
#define OFF_VT    33554432u
#define OFF_WOT   41943040u
#define OFF_QKV   58720256u

extern "C" void kernel_launch(void* const* d_in, const int* in_sizes, int n_in,
                              void* d_out, int out_size, void* d_ws, size_t ws_size,
                              hipStream_t stream) {
  const float* hs = (const float*)d_in[0];
  const int* pos = (const int*)d_in[1];
  const float* wq = (const float*)d_in[2];
  const float* wk = (const float*)d_in[3];
  const float* wv = (const float*)d_in[4];
  const float* wo = (const float*)d_in[5];
  float* out = (float*)d_out;
  char* ws = (char*)d_ws;

  u16* Xb    = (u16*)(ws + OFF_XB);
  u16* Wqkvt = (u16*)(ws + OFF_WQKVT);
  u16* Vt    = (u16*)(ws + OFF_VT);
  u16* Wot   = (u16*)(ws + OFF_WOT);
  u16* QKV   = (u16*)(ws + OFF_QKV);
  u16* AO    = (u16*)(ws + OFF_AO);

  dim3 tb(32, 8);

  // prep: convert + transposes (wq/wk/wv -> one contiguous Wqkvt [6144][2048])
  k_convert_f32_bf16<<<8192, 256, 0, stream>>>(hs, Xb, 2097152);
  k_transpose_f32_bf16<<<dim3(128, 64), tb, 0, stream>>>(wq, Wqkvt, 2048, 4096);
  k_transpose_f32_bf16<<<dim3(32, 64), tb, 0, stream>>>(wk, Wqkvt + 4096 * 2048, 2048, 1024);
  k_transpose_f32_bf16<<<dim3(32, 64), tb, 0, stream>>>(wv, Wqkvt + 5120 * 2048, 2048, 1024);
  k_transpose_f32_bf16<<<dim3(64, 128), tb, 0, stream>>>(wo, Wot, 4096, 2048);

  // fused QKV projection: [4096][2048] x [6144][2048]^T -> [4096][6144], 8-phase 256^2
  (void)hipFuncSetAttribute((const void*)k_gemm256,
                            hipFuncAttributeMaxDynamicSharedMemorySize, 131072);
  k_gemm256<<<dim3(24, 16), 512, 131072, stream>>>(Xb, Wqkvt, QKV, 6144, 2048);

  // RoPE on Q (cols 0..4095) and K (cols 4096..5119)
  k_rope<<<32768, 256, 0, stream>>>(QKV, pos, 15, 4, QKVS);
  k_rope<<<8192, 256, 0, stream>>>(QKV + 4096, pos, 3, 2, QKVS);

  // V^T (V = cols 5120..6143) -> Vt [1024][4096]
  k_transpose_bf16<<<dim3(32, 128), tb, 0, stream>>>(QKV + 5120, Vt, 4096, QKVS);

  // flash attention: split-KV, 384 blocks x 512 threads, 130 KB LDS
  k_attn<<<dim3(384), 512, 0, stream>>>(QKV, Vt, AO);

  // output projection (fp32 out), m97 structure
  k_gemm_bt<0><<<dim3(16, 32), 256, 0, stream>>>(AO, Wot, out, 4096, 2048, 4096);
}

// Round 12
// 470.853 us; speedup vs baseline: 1.0671x; 1.0671x over previous
//
#include <hip/hip_runtime.h>

typedef unsigned short u16;
typedef __bf16 bf16_t;
typedef bf16_t bf16x8 __attribute__((ext_vector_type(8)));
typedef float f32x4 __attribute__((ext_vector_type(4)));
typedef float f32x16 __attribute__((ext_vector_type(16)));

#define LOG2E 1.4426950408889634f
#define QKVS 6144  // row stride of fused QKV activation buffer

__device__ __forceinline__ u16 f2bf(float f) {
  union { float f; unsigned u; } c; c.f = f;
  unsigned r = c.u + 0x7fffu + ((c.u >> 16) & 1u);
  return (u16)(r >> 16);
}
__device__ __forceinline__ float bf2f(u16 u) {
  union { unsigned u; float f; } c; c.u = ((unsigned)u) << 16;
  return c.f;
}

__device__ __forceinline__ void gload16(const void* g, void* l) {
  __builtin_amdgcn_global_load_lds(
      (const __attribute__((address_space(1))) unsigned int*)g,
      (__attribute__((address_space(3))) unsigned int*)l, 16, 0, 0);
}

__device__ __forceinline__ unsigned cvtpk(float lo, float hi) {
  unsigned r;
  asm("v_cvt_pk_bf16_f32 %0, %1, %2" : "=v"(r) : "v"(lo), "v"(hi));
  return r;
}
__device__ __forceinline__ void swap32(unsigned& a, unsigned& b) {
  asm("v_permlane32_swap_b32 %0, %1" : "+v"(a), "+v"(b));
}

#define MFMA16(a, b, c) __builtin_amdgcn_mfma_f32_16x16x32_bf16((a), (b), (c), 0, 0, 0)
#define MFMA32(a, b, c) __builtin_amdgcn_mfma_f32_32x32x16_bf16((a), (b), (c), 0, 0, 0)

// ---------------- prep kernels ----------------

__global__ __launch_bounds__(256) void k_convert_f32_bf16(const float* __restrict__ in,
                                                          u16* __restrict__ out, int n4) {
  int i = blockIdx.x * 256 + threadIdx.x;
  if (i >= n4) return;
  float4 v = ((const float4*)in)[i];
  ushort4 o;
  o.x = f2bf(v.x); o.y = f2bf(v.y); o.z = f2bf(v.z); o.w = f2bf(v.w);
  ((ushort4*)out)[i] = o;
}

// out[C][R] = bf16(in[R][C])
__global__ __launch_bounds__(256) void k_transpose_f32_bf16(const float* __restrict__ in,
                                                            u16* __restrict__ out, int R, int C) {
  __shared__ float tile[32][33];
  int tx = threadIdx.x, ty = threadIdx.y;
  int bx = blockIdx.x * 32, by = blockIdx.y * 32;
#pragma unroll
  for (int i = 0; i < 4; i++)
    tile[ty + i * 8][tx] = in[(size_t)(by + ty + i * 8) * C + bx + tx];
  __syncthreads();
#pragma unroll
  for (int i = 0; i < 4; i++)
    out[(size_t)(bx + ty + i * 8) * R + by + tx] = f2bf(tile[tx][ty + i * 8]);
}

// out[col][row] = in[row][col]; in row-stride C, out row-stride R
__global__ __launch_bounds__(256) void k_transpose_bf16(const u16* __restrict__ in,
                                                        u16* __restrict__ out, int R, int C) {
  __shared__ u16 tile[32][33];
  int tx = threadIdx.x, ty = threadIdx.y;
  int bx = blockIdx.x * 32, by = blockIdx.y * 32;
#pragma unroll
  for (int i = 0; i < 4; i++)
    tile[ty + i * 8][tx] = in[(size_t)(by + ty + i * 8) * C + bx + tx];
  __syncthreads();
#pragma unroll
  for (int i = 0; i < 4; i++)
    out[(size_t)(bx + ty + i * 8) * R + by + tx] = tile[tx][ty + i * 8];
}

// ---------------- RoPE (in place, bf16) — used for K only ----------------
__global__ __launch_bounds__(256) void k_rope(u16* __restrict__ x, const int* __restrict__ pos,
                                              int nh_mask, int nh_shift, int width) {
  int idx = blockIdx.x * 256 + threadIdx.x;
  int i = idx & 127;
  int h = (idx >> 7) & nh_mask;
  int row = idx >> (7 + nh_shift);
  int p = pos[row];
  float f = (float)p * exp2f((float)i * (-13.287712379549449f / 128.f));
  float sn, cs;
  sincosf(f, &sn, &cs);
  size_t base = (size_t)row * width + h * 256 + i;
  float x1 = bf2f(x[base]), x2 = bf2f(x[base + 128]);
  x[base] = f2bf(x1 * cs - x2 * sn);
  x[base + 128] = f2bf(x2 * cs + x1 * sn);
}

// ---------------- GEMM m97-style (kept for out-proj) ----------------

template <int OUT_BF16>
__global__ __launch_bounds__(256) void k_gemm_bt(const u16* __restrict__ A,
                                                 const u16* __restrict__ Bt,
                                                 void* __restrict__ C, int M, int N, int K) {
  __shared__ u16 As[128 * 64];
  __shared__ u16 Bs[128 * 64];
  const int tid = threadIdx.x;
  const int lane = tid & 63;
  const int w = tid >> 6;
  const int l15 = lane & 15, l4 = lane >> 4;
  const int wr = w >> 1, wc = w & 1;
  const int bx = blockIdx.x, by = blockIdx.y;

  f32x4 acc[4][4];
#pragma unroll
  for (int a = 0; a < 4; a++)
#pragma unroll
    for (int b2 = 0; b2 < 4; b2++) acc[a][b2] = (f32x4){0.f, 0.f, 0.f, 0.f};

  const u16* Abase = A + (size_t)by * 128 * K;
  const u16* Bbase = Bt + (size_t)bx * 128 * K;

  for (int kk = 0; kk < K; kk += 64) {
    __syncthreads();
#pragma unroll
    for (int j = 0; j < 4; j++) {
      int ci = w * 256 + j * 64 + lane;
      int row = ci >> 3, c = ci & 7;
      gload16(Abase + (size_t)row * K + kk + c * 8, (char*)As + ci * 16);
      gload16(Bbase + (size_t)row * K + kk + c * 8, (char*)Bs + ci * 16);
    }
    __syncthreads();
#pragma unroll
    for (int kc = 0; kc < 2; kc++) {
      int kb = kc * 64 + l4 * 16;
      bf16x8 av[4], bv[4];
#pragma unroll
      for (int mt = 0; mt < 4; mt++)
        av[mt] = *(const bf16x8*)((const char*)As + (wr * 64 + mt * 16 + l15) * 128 + kb);
#pragma unroll
      for (int nt = 0; nt < 4; nt++)
        bv[nt] = *(const bf16x8*)((const char*)Bs + (wc * 64 + nt * 16 + l15) * 128 + kb);
#pragma unroll
      for (int mt = 0; mt < 4; mt++)
#pragma unroll
        for (int nt = 0; nt < 4; nt++) acc[mt][nt] = MFMA16(av[mt], bv[nt], acc[mt][nt]);
    }
  }
#pragma unroll
  for (int mt = 0; mt < 4; mt++) {
#pragma unroll
    for (int nt = 0; nt < 4; nt++) {
      int col = bx * 128 + wc * 64 + nt * 16 + l15;
#pragma unroll
      for (int r = 0; r < 4; r++) {
        int row = by * 128 + wr * 64 + mt * 16 + l4 * 4 + r;
        if (OUT_BF16)
          ((u16*)C)[(size_t)row * N + col] = f2bf(acc[mt][nt][r]);
        else
          ((float*)C)[(size_t)row * N + col] = acc[mt][nt][r];
      }
    }
  }
}

// ---------------- GEMM 256x256 8-phase (r10, race-safe) ----------------

__global__ __launch_bounds__(512, 1) void k_gemm256(const u16* __restrict__ A,
                                                    const u16* __restrict__ Bt,
                                                    u16* __restrict__ C, int N, int K) {
  extern __shared__ char smem[];
  const int tid = threadIdx.x;
  const int lane = tid & 63, w = tid >> 6;
  const int l15 = lane & 15, l4 = lane >> 4;
  const int wr = w >> 2, wc = w & 3;
  const int bx = blockIdx.x, by = blockIdx.y;
  const int NT = K >> 6;

  const u16* Ab = A + (size_t)(by * 256) * K;
  const u16* Bb = Bt + (size_t)(bx * 256) * K;

  int srcoff[2], dstoff[2];
#pragma unroll
  for (int rr = 0; rr < 2; rr++) {
    int ci = rr * 512 + tid;
    int lc = ci ^ (((ci >> 5) & 1) << 1);
    int kc = lc >> 9, row = (lc >> 2) & 127, g2 = lc & 3;
    srcoff[rr] = row * K + kc * 32 + g2 * 8;
    dstoff[rr] = ci * 16;
  }

  auto SH = [&](int Tg, int halfidx) {
    const u16* base = (halfidx < 2) ? (Ab + (size_t)(halfidx * 128) * K)
                                    : (Bb + (size_t)((halfidx - 2) * 128) * K);
    char* dst = smem + (Tg & 1) * 65536 + halfidx * 16384;
    int kk = Tg * 64;
#pragma unroll
    for (int rr = 0; rr < 2; rr++)
      gload16(base + srcoff[rr] + kk, dst + dstoff[rr]);
  };

  auto lda = [&](int c, int kc, int mrow4) -> bf16x8 {
    int L = kc * 8192 + (mrow4 * 16 + l15) * 64 + l4 * 16;
    int P = L ^ (((L >> 9) & 1) << 5);
    return *(const bf16x8*)(smem + c * 65536 + wr * 16384 + P);
  };
  auto ldb = [&](int c, int kc, int j) -> bf16x8 {
    int L = kc * 8192 + ((wc & 1) * 64 + j * 16 + l15) * 64 + l4 * 16;
    int P = L ^ (((L >> 9) & 1) << 5);
    return *(const bf16x8*)(smem + c * 65536 + 32768 + (wc >> 1) * 16384 + P);
  };

  f32x4 acc[8][4];
#pragma unroll
  for (int i = 0; i < 8; i++)
#pragma unroll
    for (int j = 0; j < 4; j++) acc[i][j] = (f32x4){0.f, 0.f, 0.f, 0.f};

  SH(0, 0); SH(0, 1); SH(0, 2); SH(0, 3);
  SH(1, 2); SH(1, 3);
  asm volatile("s_waitcnt vmcnt(4)" ::: "memory");
  __builtin_amdgcn_s_barrier();
  asm volatile("" ::: "memory");

  bf16x8 bv[2][4];
  for (int T = 0; T < NT; ++T) {
    const int c = T & 1;
#pragma unroll
    for (int q = 0; q < 4; q++) {
      const int kc = q & 1, mh = q >> 1;
      bf16x8 av[4];
      if (q < 2) {
#pragma unroll
        for (int j = 0; j < 4; j++) bv[kc][j] = ldb(c, kc, j);
      }
#pragma unroll
      for (int ii = 0; ii < 4; ii++) av[ii] = lda(c, kc, mh * 4 + ii);
      if (q == 0)      { if (T + 1 < NT) SH(T + 1, 0); }
      else if (q == 1) { if (T + 1 < NT) SH(T + 1, 1); }
      else if (q == 2) { if (T + 2 < NT) SH(T + 2, 2); }
      else             { if (T + 2 < NT) SH(T + 2, 3); }
      if (q == 3) {
        if (T < NT - 2)       asm volatile("s_waitcnt vmcnt(4)" ::: "memory");
        else if (T == NT - 2) asm volatile("s_waitcnt vmcnt(0)" ::: "memory");
      }
      asm volatile("" ::: "memory");
      __builtin_amdgcn_s_barrier();
      asm volatile("" ::: "memory");
      asm volatile("s_waitcnt lgkmcnt(0)" ::: "memory");
      __builtin_amdgcn_sched_barrier(0);
      __builtin_amdgcn_s_setprio(1);
#pragma unroll
      for (int ii = 0; ii < 4; ii++)
#pragma unroll
        for (int j = 0; j < 4; j++)
          acc[mh * 4 + ii][j] = MFMA16(av[ii], bv[kc][j], acc[mh * 4 + ii][j]);
      __builtin_amdgcn_s_setprio(0);
      asm volatile("" ::: "memory");
      __builtin_amdgcn_s_barrier();
      asm volatile("" ::: "memory");
    }
  }

#pragma unroll
  for (int i = 0; i < 8; i++) {
#pragma unroll
    for (int j = 0; j < 4; j++) {
      int col = bx * 256 + wc * 64 + j * 16 + l15;
#pragma unroll
      for (int r = 0; r < 4; r++) {
        int row = by * 256 + wr * 128 + i * 16 + l4 * 4 + r;
        C[(size_t)row * N + col] = f2bf(acc[i][j][r]);
      }
    }
  }
}

// ---------------- flash attention (r10 shell + batched LDS reads + fused RoPE-Q) ----------------
// 512 blocks x 256 thr (4 waves), 2 blocks/CU, XCD-pinned (b,kv) = flat%8.
// Batched fragment reads (8-deep) pipeline the ~120cy LDS latency instead of
// serializing it per-read (VGPR headroom: o128 + qreg64 + batch32 < 256).
// RoPE applied to Q in-register at load (lane holds both halves of each pair).

__shared__ __align__(16) u16 aK0[8192];
__shared__ __align__(16) u16 aK1[8192];
__shared__ __align__(16) u16 aV0[8192];
__shared__ __align__(16) u16 aV1[8192];

__global__ __launch_bounds__(256, 2) void k_attn(const u16* __restrict__ QKV,
                                                 const u16* __restrict__ Vt,
                                                 const int* __restrict__ pos,
                                                 u16* __restrict__ AO) {
  const int tid = threadIdx.x, lane = tid & 63, w = tid >> 6;
  const int r31 = lane & 31, hi = lane >> 5;

  const int flat = blockIdx.x;
  const int r = flat & 7;            // XCD (round-robin dispatch)
  const int idx = flat >> 3;
  const int b = r >> 2, kv = r & 3;  // one (b,kv) per XCD: 2 MB K/V, L2-resident
  const int half = idx >> 5, j = idx & 31;
  const int qb = half ? 15 - (j >> 1) : (j >> 1);
  const int h = kv * 4 + (j & 1) + 2 * half;

  const int qloc = qb * 128 + w * 32 + r31;

  // ---- Q fragments + in-register RoPE ----
  bf16x8 qreg[16];
  {
    const u16* qp = QKV + (size_t)(b * 2048 + qloc) * QKVS + h * 256 + hi * 8;
#pragma unroll
    for (int kc = 0; kc < 16; kc++) qreg[kc] = *(const bf16x8*)(qp + kc * 16);
    float pp = (float)pos[b * 2048 + qloc];
    union BU { bf16x8 v; u16 a[8]; };
#pragma unroll
    for (int kc = 0; kc < 8; kc++) {
      BU lo, hh;
      lo.v = qreg[kc];
      hh.v = qreg[kc + 8];
#pragma unroll
      for (int e = 0; e < 8; e++) {
        int i = kc * 16 + hi * 8 + e;
        float f = pp * exp2f((float)i * (-13.287712379549449f / 128.f));
        float sn, cs;
        sincosf(f, &sn, &cs);
        float x1 = bf2f(lo.a[e]), x2 = bf2f(hh.a[e]);
        lo.a[e] = f2bf(x1 * cs - x2 * sn);
        hh.a[e] = f2bf(x2 * cs + x1 * sn);
      }
      qreg[kc] = lo.v;
      qreg[kc + 8] = hh.v;
    }
  }

  f32x16 o[8];
#pragma unroll
  for (int df = 0; df < 8; df++)
#pragma unroll
    for (int jj = 0; jj < 16; jj++) o[df][jj] = 0.f;
  float mrow = -3e38f, lrow = 0.f;

  const int nt = 4 * qb + 4;  // always even
  const int tlim = 4 * qb + w;
  const u16* Kbase = QKV + (size_t)(b * 2048) * QKVS + 4096 + kv * 256;
  const u16* Vbase = Vt + (size_t)(kv * 256) * 4096 + b * 2048;

  int kfix[4], vfix[4];
#pragma unroll
  for (int jj = 0; jj < 4; jj++) {
    int ci = jj * 256 + tid;
    int krow = ci >> 5, kc = ci & 31;
    int kcg = (kc & 24) | ((kc ^ krow) & 7);
    kfix[jj] = krow * QKVS + kcg * 8;
    int vrow = ci >> 2, vc = ci & 3;
    int vg = (vc - (vrow >> 1)) & 3;
    vfix[jj] = vrow * 4096 + vg * 8;
  }
  int koff = 0, voff = 0;

  auto STAGE = [&](u16* Kd, u16* Vd) {
#pragma unroll
    for (int jj = 0; jj < 4; jj++)
      gload16(Kbase + kfix[jj] + koff, (char*)Kd + (jj * 256 + tid) * 16);
#pragma unroll
    for (int jj = 0; jj < 4; jj++)
      gload16(Vbase + vfix[jj] + voff, (char*)Vd + (jj * 256 + tid) * 16);
    koff += 32 * QKVS;
    voff += 32;
  };

  auto COMPUTE = [&](int t, const u16* Kc, const u16* Vc) {
    // ---- QK^T swapped, batched 8-deep LDS reads ----
    f32x16 s;
#pragma unroll
    for (int jj = 0; jj < 16; jj++) s[jj] = 0.f;
#pragma unroll
    for (int hf = 0; hf < 2; hf++) {
      bf16x8 kb[8];
#pragma unroll
      for (int k2 = 0; k2 < 8; k2++) {
        int kc = hf * 8 + k2;
        int ch = kc * 2 + hi;
        int cs = (ch & 24) | ((ch ^ r31) & 7);
        kb[k2] = *(const bf16x8*)((const char*)Kc + r31 * 512 + cs * 16);
      }
#pragma unroll
      for (int k2 = 0; k2 < 8; k2++) s = MFMA32(kb[k2], qreg[hf * 8 + k2], s);
    }

    const float C = 0.0625f * LOG2E;
    float z[16];
#pragma unroll
    for (int jj = 0; jj < 16; jj++) z[jj] = s[jj] * C;
    if (t == tlim) {
#pragma unroll
      for (int jj = 0; jj < 16; jj++) {
        int kvg = t * 32 + (jj & 3) + 8 * (jj >> 2) + 4 * hi;
        if (kvg > qloc) z[jj] = -1e30f;
      }
    }

    float m0 = z[0];
#pragma unroll
    for (int jj = 1; jj < 16; jj++) m0 = fmaxf(m0, z[jj]);
    m0 = fmaxf(m0, __shfl_xor(m0, 32));
    if (__any(m0 > mrow + 11.54f)) {  // rare after first tile
      float mn = fmaxf(mrow, m0);
      float alpha = exp2f(mrow - mn);
      mrow = mn;
      lrow *= alpha;
#pragma unroll
      for (int jj = 0; jj < 16; jj++) {
        float a = __shfl(alpha, (jj & 3) + 8 * (jj >> 2) + 4 * hi);
#pragma unroll
        for (int df = 0; df < 8; df++) o[df][jj] *= a;
      }
    }
    float sum = 0.f;
#pragma unroll
    for (int jj = 0; jj < 16; jj++) {
      z[jj] = exp2f(z[jj] - mrow);
      sum += z[jj];
    }
    sum += __shfl_xor(sum, 32);
    lrow += sum;

    unsigned a0 = cvtpk(z[0], z[1]), a2 = cvtpk(z[4], z[5]);
    swap32(a0, a2);
    unsigned a1 = cvtpk(z[2], z[3]), a3 = cvtpk(z[6], z[7]);
    swap32(a1, a3);
    unsigned b0 = cvtpk(z[8], z[9]), b2 = cvtpk(z[12], z[13]);
    swap32(b0, b2);
    unsigned b1 = cvtpk(z[10], z[11]), b3 = cvtpk(z[14], z[15]);
    swap32(b1, b3);
    union UU { unsigned u[4]; bf16x8 v; };
    UU ua; ua.u[0] = a0; ua.u[1] = a1; ua.u[2] = a2; ua.u[3] = a3;
    UU ub; ub.u[0] = b0; ub.u[1] = b1; ub.u[2] = b2; ub.u[3] = b3;
    bf16x8 pa0 = ua.v, pa1 = ub.v;

    // ---- PV, batched 8-deep V reads ----
#pragma unroll
    for (int hf = 0; hf < 2; hf++) {
      bf16x8 vb[8];
#pragma unroll
      for (int df = 0; df < 8; df++) {
        int vr = df * 32 + r31;
        int cc = (hf * 2 + hi + (vr >> 1)) & 3;
        vb[df] = *(const bf16x8*)((const char*)Vc + vr * 64 + cc * 16);
      }
#pragma unroll
      for (int df = 0; df < 8; df++)
        o[df] = MFMA32(hf ? pa1 : pa0, vb[df], o[df]);
    }
  };

  STAGE(aK0, aV0);
  __syncthreads();

  for (int t = 0; t < nt; t += 2) {
    STAGE(aK1, aV1);
    if (t <= tlim) COMPUTE(t, aK0, aV0);
    __syncthreads();
    if (t + 2 < nt) STAGE(aK0, aV0);
    if (t + 1 <= tlim) COMPUTE(t + 1, aK1, aV1);
    __syncthreads();
  }

  float rl = 1.f / lrow;
  size_t rowbase = (size_t)(b * 2048 + qb * 128 + w * 32);
#pragma unroll
  for (int jj = 0; jj < 16; jj++) {
    float rr2 = __shfl(rl, (jj & 3) + 8 * (jj >> 2) + 4 * hi);
    int qr = (jj & 3) + 8 * (jj >> 2) + 4 * hi;
#pragma unroll
    for (int df = 0; df < 8; df++)
      AO[(rowbase + qr) * 4096 + h * 256 + df * 32 + r31] = f2bf(o[df][jj] * rr2);
  }
}

// ---------------- host ----------------

// ws layout (bytes), high-water 109.1 MB:
// Xb @0 (16MB, dead after QKV gemm) -- AO @0 (32MB) aliases it + Wqkvt head.
// Wqkvt @16.7M (24MB), dead after gemm. Vt @33.5M (8MB) aliases Wqkvt tail.
// Wot @41.9M (16MB, persists). QKV @58.7M (48MB, [4096][6144]).
#define OFF_AO    0u
#define OFF_XB    0u
#define OFF_WQKVT 16777216u
#define OFF_VT    33554432u
#define OFF_WOT   41943040u
#define OFF_QKV   58720256u

extern "C" void kernel_launch(void* const* d_in, const int* in_sizes, int n_in,
                              void* d_out, int out_size, void* d_ws, size_t ws_size,
                              hipStream_t stream) {
  const float* hs = (const float*)d_in[0];
  const int* pos = (const int*)d_in[1];
  const float* wq = (const float*)d_in[2];
  const float* wk = (const float*)d_in[3];
  const float* wv = (const float*)d_in[4];
  const float* wo = (const float*)d_in[5];
  float* out = (float*)d_out;
  char* ws = (char*)d_ws;

  u16* Xb    = (u16*)(ws + OFF_XB);
  u16* Wqkvt = (u16*)(ws + OFF_WQKVT);
  u16* Vt    = (u16*)(ws + OFF_VT);
  u16* Wot   = (u16*)(ws + OFF_WOT);
  u16* QKV   = (u16*)(ws + OFF_QKV);
  u16* AO    = (u16*)(ws + OFF_AO);

  dim3 tb(32, 8);

  // prep: convert + transposes (wq/wk/wv -> one contiguous Wqkvt [6144][2048])
  k_convert_f32_bf16<<<8192, 256, 0, stream>>>(hs, Xb, 2097152);
  k_transpose_f32_bf16<<<dim3(128, 64), tb, 0, stream>>>(wq, Wqkvt, 2048, 4096);
  k_transpose_f32_bf16<<<dim3(32, 64), tb, 0, stream>>>(wk, Wqkvt + 4096 * 2048, 2048, 1024);
  k_transpose_f32_bf16<<<dim3(32, 64), tb, 0, stream>>>(wv, Wqkvt + 5120 * 2048, 2048, 1024);
  k_transpose_f32_bf16<<<dim3(64, 128), tb, 0, stream>>>(wo, Wot, 4096, 2048);

  // fused QKV projection: [4096][2048] x [6144][2048]^T -> [4096][6144], 8-phase 256^2
  (void)hipFuncSetAttribute((const void*)k_gemm256,
                            hipFuncAttributeMaxDynamicSharedMemorySize, 131072);
  k_gemm256<<<dim3(24, 16), 512, 131072, stream>>>(Xb, Wqkvt, QKV, 6144, 2048);

  // RoPE on K only (cols 4096..5119); Q rope is fused into k_attn
  k_rope<<<8192, 256, 0, stream>>>(QKV + 4096, pos, 3, 2, QKVS);

  // V^T (V = cols 5120..6143) -> Vt [1024][4096]
  k_transpose_bf16<<<dim3(32, 128), tb, 0, stream>>>(QKV + 5120, Vt, 4096, QKVS);

  // flash attention (r10 shell, XCD-pinned, batched reads, fused rope-Q)
  k_attn<<<dim3(512), 256, 0, stream>>>(QKV, Vt, pos, AO);

  // output projection (fp32 out), m97 structure
  k_gemm_bt<0><<<dim3(16, 32), 256, 0, stream>>>(AO, Wot, out, 4096, 2048, 4096);
}